// Round 2
// baseline (1095.995 us; speedup 1.0000x reference)
//
#include <hip/hip_runtime.h>
#include <hip/hip_bf16.h>
#include <cstddef>

// EfficientAttention pipeline, MI355X. All inputs/outputs fp32 (per reference dtypes;
// threshold analysis R1 confirmed no bf16 eps-floor => fp32 tensors).
// B=64, DIM=128, N=4000, H=4, DH=32, CL=50, K=9.
// ws usage: ~33.9M floats (~136 MB).

// ---- workspace offsets (in floats) ----
constexpr size_t O_MU    = 0;                    // 8192  per-(b,c) mean
constexpr size_t O_RINV  = O_MU    + 8192;       // 8192  rsqrt(var+1e-3)
constexpr size_t O_RATIO = O_RINV  + 8192;       // 8192  var/(var+1e-3)
constexpr size_t O_A1    = O_RATIO + 8192;       // 128   g1_gamma*inv2
constexpr size_t O_B1    = O_A1    + 128;        // 128   g1_beta
constexpr size_t O_A2    = O_B1    + 128;        // 128
constexpr size_t O_B2    = O_A2    + 128;        // 128
constexpr size_t O_W1T   = O_B2    + 128;        // 128*64 wg1 transposed [c][cl]
constexpr size_t O_W2T   = O_W1T   + 8192;       // 128*64
constexpr size_t O_BG1   = O_W2T   + 8192;       // 64
constexpr size_t O_BG2   = O_BG1   + 64;         // 64
constexpr size_t O_PRESWT= O_BG2   + 64;         // 256*128 pres_w^T [k][o]
constexpr size_t O_PROJWT= O_PRESWT+ 32768;      // 128*128 proj_w^T [k][o]
constexpr size_t O_PRESB = O_PROJWT+ 16384;      // 128
constexpr size_t O_E1    = O_PRESB + 128;        // 64*50*4000 embed1 (pre-softmax)
constexpr size_t O_E2    = O_E1    + 12800000;   // 64*50*4000 embed2 (pre-softmax)
constexpr size_t O_RMAX  = O_E2    + 12800000;   // 3200 row max (b,cl)
constexpr size_t O_RSINV = O_RMAX  + 3200;       // 3200 1/rowsum
constexpr size_t O_CXP   = O_RSINV + 3200;       // 8*64*128*50 partial cluster_x
constexpr size_t O_CX    = O_CXP   + 3276800;    // 64*128*50 cluster_x [b][d][c]
constexpr size_t O_XT    = O_CX    + 409600;     // 64*4*50*32 q-proj points [b][h][c][d]
constexpr size_t O_QT    = O_XT    + 409600;
constexpr size_t O_KT    = O_QT    + 409600;
constexpr size_t O_VT    = O_KT    + 409600;
constexpr size_t O_H1    = O_VT    + 409600;     // 64*4*150*32 conv1 pre-BN [b][h][n*3+j][o]
constexpr size_t O_P1    = O_H1    + 1228800;    // 64*256 BN1 partials [b][128 sum |128 sq]
constexpr size_t O_BN1S  = O_P1    + 16384;      // 128
constexpr size_t O_BN1T  = O_BN1S  + 128;        // 128
constexpr size_t O_H2    = O_BN1T  + 128;        // 64*4*50*32 conv2 pre-BN [b][h][n][o]
constexpr size_t O_P2    = O_H2    + 409600;     // 256*64 BN2 partials [(b*4+h)][32 sum|32 sq]
constexpr size_t O_BN2S  = O_P2    + 16384;      // 128
constexpr size_t O_BN2T  = O_BN2S  + 128;        // 128
constexpr size_t O_CAT   = O_BN2T  + 128;        // 64*256*50 concat channels [b][ch][n]
constexpr size_t O_PRES2 = O_CAT   + 819200;     // 64*128*50 proj_w@(res+pres_b) [b][o][c]

// ---------------- K1: per-(b,c) instance-norm stats over n=4000 ----------------
__global__ __launch_bounds__(256) void k_rowstats(const float* __restrict__ x,
                                                  float* __restrict__ ws){
  int row = blockIdx.x;                       // b*128+c
  const float4* xr = (const float4*)(x + (size_t)row * 4000); // 1000 float4
  float s = 0.f, sq = 0.f;
  for(int i = threadIdx.x; i < 1000; i += 256){
    float4 v = xr[i];
    s  += v.x + v.y + v.z + v.w;
    sq += v.x*v.x + v.y*v.y + v.z*v.z + v.w*v.w;
  }
  __shared__ float ls[256], lq[256];
  ls[threadIdx.x] = s; lq[threadIdx.x] = sq; __syncthreads();
  for(int st = 128; st > 0; st >>= 1){
    if(threadIdx.x < st){ ls[threadIdx.x] += ls[threadIdx.x+st]; lq[threadIdx.x] += lq[threadIdx.x+st]; }
    __syncthreads();
  }
  if(threadIdx.x == 0){
    float mean = ls[0] * (1.f/4000.f);
    float var  = lq[0] * (1.f/4000.f) - mean*mean;
    ws[O_MU   + row] = mean;
    ws[O_RINV + row] = rsqrtf(var + 1e-3f);
    ws[O_RATIO+ row] = var / (var + 1e-3f);
  }
}

// ---------------- K2: channel BN stats (mu2==0 exactly) + weight prep ----------------
__global__ void k_prep(const float* g1g, const float* g1b,
                       const float* g2g, const float* g2b,
                       const float* wg1, const float* bg1,
                       const float* wg2, const float* bg2,
                       const float* presw, const float* presb,
                       const float* projw,
                       float* __restrict__ ws){
  int t = threadIdx.x;
  if(t < 128){
    float s = 0.f;
    for(int b = 0; b < 64; b++) s += ws[O_RATIO + b*128 + t];
    float var2 = s * (1.f/64.f);
    float inv2 = rsqrtf(var2 + 1e-5f);
    ws[O_A1+t] = g1g[t] * inv2;  ws[O_B1+t] = g1b[t];
    ws[O_A2+t] = g2g[t] * inv2;  ws[O_B2+t] = g2b[t];
  }
  for(int i = t; i < 8192; i += 256){
    int c = i >> 6, cl = i & 63;
    ws[O_W1T+i] = (cl < 50) ? wg1[cl*128 + c] : 0.f;
    ws[O_W2T+i] = (cl < 50) ? wg2[cl*128 + c] : 0.f;
  }
  if(t < 50){ ws[O_BG1+t] = bg1[t]; ws[O_BG2+t] = bg2[t]; }
  for(int i = t; i < 32768; i += 256){ int o = i & 127, k = i >> 7; ws[O_PRESWT+i] = presw[o*256 + k]; }
  for(int i = t; i < 16384; i += 256){ int o = i & 127, k = i >> 7; ws[O_PROJWT+i] = projw[o*128 + k]; }
  if(t < 128) ws[O_PRESB+t] = presb[t];
}

// ---------------- K3: embed1/embed2 = Wg @ relu(affine(x))  ----------------
__global__ __launch_bounds__(256) void k_embed(const float* __restrict__ x,
                                               float* __restrict__ ws){
  int b = blockIdx.y, n0 = blockIdx.x * 64;
  __shared__ float r1[128][64];   // 32 KB
  __shared__ float r2[128][64];   // 32 KB  (total exactly 64 KB)
  int t = threadIdx.x;
  for(int i = t; i < 8192; i += 256){
    int c = i >> 6, j = i & 63, n = n0 + j;
    float mu = ws[O_MU + b*128 + c], ri = ws[O_RINV + b*128 + c];
    float a1 = ws[O_A1+c] * ri, b1 = ws[O_B1+c] - a1*mu;
    float a2 = ws[O_A2+c] * ri, b2 = ws[O_B2+c] - a2*mu;
    float xv = (n < 4000) ? x[(size_t)(b*128 + c)*4000 + n] : 0.f;
    r1[c][j] = fmaxf(a1*xv + b1, 0.f);
    r2[c][j] = fmaxf(a2*xv + b2, 0.f);
  }
  __syncthreads();
  int w    = __builtin_amdgcn_readfirstlane(t >> 6);
  int lane = t & 63;
  int g    = w >> 1;
  int clb  = (w & 1) * 25;
  const float* wt = ws + (g ? O_W2T : O_W1T) + clb;
  const float (*r)[64] = g ? r2 : r1;
  float acc[25];
  #pragma unroll
  for(int i = 0; i < 25; i++) acc[i] = 0.f;
  for(int c = 0; c < 128; c++){
    float rv = r[c][lane];
    const float* wr = wt + c*64;
    #pragma unroll
    for(int i = 0; i < 25; i++) acc[i] += wr[i] * rv;
  }
  int n = n0 + lane;
  if(n < 4000){
    const float* bg = ws + (g ? O_BG2 : O_BG1);
    float* e = ws + (g ? O_E2 : O_E1) + (size_t)b*200000 + n;
    #pragma unroll
    for(int i = 0; i < 25; i++) e[(size_t)(clb+i)*4000] = acc[i] + bg[clb+i];
  }
}

// ---------------- K4: softmax-over-n row stats for embed1 ----------------
__global__ __launch_bounds__(256) void k_rowsm(float* __restrict__ ws){
  int row = blockIdx.x;                 // b*50+cl
  const float* e = ws + O_E1 + (size_t)row * 4000;
  int t = threadIdx.x;
  float vals[16];
  float m = -INFINITY;
  #pragma unroll
  for(int i = 0; i < 16; i++){
    int n = t + i*256;
    float v = (n < 4000) ? e[n] : -INFINITY;
    vals[i] = v; m = fmaxf(m, v);
  }
  __shared__ float red[256];
  red[t] = m; __syncthreads();
  for(int st = 128; st > 0; st >>= 1){ if(t < st) red[t] = fmaxf(red[t], red[t+st]); __syncthreads(); }
  float M = red[0];
  __syncthreads();
  float s = 0.f;
  #pragma unroll
  for(int i = 0; i < 16; i++) s += expf(vals[i] - M);   // exp(-inf)=0 for pads
  red[t] = s; __syncthreads();
  for(int st = 128; st > 0; st >>= 1){ if(t < st) red[t] += red[t+st]; __syncthreads(); }
  if(t == 0){ ws[O_RMAX+row] = M; ws[O_RSINV+row] = 1.f / red[0]; }
}

// ---------------- K5: cluster_x partials:  cx[b,d,c] = sum_n x * softmax(e1) ----------------
__global__ __launch_bounds__(256) void k_cxp(const float* __restrict__ x,
                                             float* __restrict__ ws){
  int b = blockIdx.y, ch = blockIdx.x;        // 8 chunks of 500 points
  __shared__ float xT[64][129];               // [j][d] pad->conflict-free
  __shared__ float pl[50][64];                // [c][j]
  int t = threadIdx.x;
  int w = __builtin_amdgcn_readfirstlane(t >> 6);
  int lane = t & 63;
  int d  = lane + (w & 1)*64;
  int cb = (w >> 1) * 25;
  float acc[25];
  #pragma unroll
  for(int i = 0; i < 25; i++) acc[i] = 0.f;
  int nbase = ch * 500;
  for(int tile = 0; tile < 8; tile++){
    int n0  = nbase + tile*64;
    int lim = min(64, nbase + 500 - n0);      // last tile: 52
    __syncthreads();
    for(int i = t; i < 8192; i += 256){
      int dd = i >> 6, j = i & 63;
      xT[j][dd] = (j < lim) ? x[(size_t)(b*128 + dd)*4000 + n0 + j] : 0.f;
    }
    for(int i = t; i < 3200; i += 256){
      int c = i >> 6, j = i & 63;
      float v = 0.f;
      if(j < lim){
        int row = b*50 + c;
        v = expf(ws[O_E1 + (size_t)row*4000 + n0 + j] - ws[O_RMAX+row]) * ws[O_RSINV+row];
      }
      pl[c][j] = v;
    }
    __syncthreads();
    for(int j = 0; j < 64; j++){
      float xv = xT[j][d];
      #pragma unroll
      for(int i = 0; i < 25; i++) acc[i] += pl[cb+i][j] * xv;
    }
  }
  float* o = ws + O_CXP + ((size_t)(ch*64 + b)*128 + d)*50 + cb;
  #pragma unroll
  for(int i = 0; i < 25; i++) o[i] = acc[i];
}

__global__ void k_cxsum(float* __restrict__ ws){
  int idx = blockIdx.x*256 + threadIdx.x;     // 409600
  if(idx < 409600){
    float s = 0.f;
    for(int ch = 0; ch < 8; ch++) s += ws[O_CXP + (size_t)ch*409600 + idx];
    ws[O_CX + idx] = s;
  }
}

// ---------------- K6: qkv + qkv1 projections (512x128 @ 128x50 per b) ----------------
__global__ __launch_bounds__(256) void k_qkv(const float* __restrict__ qw,
                                             const float* __restrict__ qb,
                                             const float* __restrict__ q1w,
                                             const float* __restrict__ q1b,
                                             float* __restrict__ ws){
  int b = blockIdx.y, rt = blockIdx.x;        // 8 row-tiles of 64
  __shared__ float wl[128][65];               // [k][rl]
  __shared__ float cxl[128][52];              // [k][c] (cols 50,51 zero-pad)
  int t = threadIdx.x;
  for(int i = t; i < 6656; i += 256){
    int k = i / 52, c = i % 52;
    cxl[k][c] = (c < 50) ? ws[O_CX + (size_t)(b*128 + k)*50 + c] : 0.f;
  }
  for(int i = t; i < 8192; i += 256){
    int k = i & 127, rl = i >> 7, row = rt*64 + rl;
    wl[k][rl] = (row < 128) ? qw[row*128 + k] : q1w[(row-128)*128 + k];
  }
  __syncthreads();
  int w  = __builtin_amdgcn_readfirstlane(t >> 6);
  int rl = t & 63;
  int cb = w * 13;                            // 0,13,26,39 (cols 50/51 garbage, guarded)
  float acc[13];
  #pragma unroll
  for(int i = 0; i < 13; i++) acc[i] = 0.f;
  for(int k = 0; k < 128; k++){
    float wv = wl[k][rl];
    #pragma unroll
    for(int i = 0; i < 13; i++) acc[i] += cxl[k][cb+i] * wv;
  }
  int row = rt*64 + rl;
  size_t base; float bias;
  if(row < 128){
    int h = row >> 5;
    bias = qb[row];
    base = O_XT + (size_t)(b*4 + h)*1600 + (row & 31);
  }else{
    int r2 = row - 128, h = r2/96, j = r2%96, kind = j >> 5, dd = j & 31;
    bias = q1b[r2];
    base = (kind==0 ? O_QT : kind==1 ? O_KT : O_VT) + (size_t)(b*4 + h)*1600 + dd;
  }
  #pragma unroll
  for(int i = 0; i < 13; i++){
    int c = cb + i;
    if(c < 50) ws[base + (size_t)c*32] = acc[i] + bias;
  }
}

// ---------------- K7: knn (top-9, jax tie order) + edge + conv1 ----------------
__global__ __launch_bounds__(256) void k_knn(const float* __restrict__ g1w,
                                             const float* __restrict__ g1bias,
                                             float* __restrict__ ws){
  int h = blockIdx.x, b = blockIdx.y;
  __shared__ float xtl[50][33];
  __shared__ float pdl[50][52];
  __shared__ float sql[50];
  __shared__ int   idxl[50][9];
  __shared__ float w1l[6144];                 // [(i*3+t)*32+o]
  int t = threadIdx.x;
  const float* xtg = ws + O_XT + (size_t)(b*4 + h)*1600;
  for(int i = t; i < 1600; i += 256) xtl[i >> 5][i & 31] = xtg[i];
  for(int i = t; i < 6144; i += 256){
    int o = i / 192, r = i % 192, ii = r / 3, tt = r % 3;
    w1l[(ii*3 + tt)*32 + o] = g1w[(size_t)h*6144 + i];
  }
  __syncthreads();
  if(t < 50){
    float s = 0.f;
    for(int d = 0; d < 32; d++){ float v = xtl[t][d]; s += v*v; }
    sql[t] = s;
  }
  __syncthreads();
  for(int i = t; i < 2500; i += 256){
    int n = i / 50, m = i % 50;
    float s = 0.f;
    for(int d = 0; d < 32; d++) s += xtl[n][d]*xtl[m][d];
    pdl[n][m] = 2.f*s - sql[n] - sql[m];
  }
  __syncthreads();
  if(t < 50){
    float pv = INFINITY; int pi = -1;
    for(int k = 0; k < 9; k++){
      float bv = -INFINITY; int bi = 1000;
      for(int m = 0; m < 50; m++){
        float v = pdl[t][m];
        bool elig = (v < pv) || (v == pv && m > pi);
        if(elig && (v > bv || (v == bv && m < bi))){ bv = v; bi = m; }
      }
      idxl[t][k] = bi; pv = bv; pi = bi;
    }
  }
  __syncthreads();
  if(t < 150){
    int n = t / 3, jw = t % 3;
    float acc[32];
    #pragma unroll
    for(int o = 0; o < 32; o++) acc[o] = 0.f;
    for(int t3 = 0; t3 < 3; t3++){
      int kx = idxl[n][jw*3 + t3];
      for(int ii = 0; ii < 32; ii++){
        float c0 = xtl[n][ii];
        float c1 = c0 - xtl[kx][ii];
        const float* wr0 = w1l + (ii*3 + t3)*32;
        const float* wr1 = w1l + ((ii+32)*3 + t3)*32;
        #pragma unroll
        for(int o = 0; o < 32; o++) acc[o] += c0*wr0[o] + c1*wr1[o];
      }
    }
    float* out = ws + O_H1 + ((size_t)(b*4 + h)*150 + n*3 + jw)*32;
    #pragma unroll
    for(int o = 0; o < 32; o++) out[o] = acc[o] + g1bias[h*32 + o];
  }
}

// ---------------- K8: BN1 stats ----------------
__global__ void k_bn1p(float* __restrict__ ws){
  int b = blockIdx.x, t = threadIdx.x;
  int p = t & 127, half = t >> 7;
  int h = p >> 5, o = p & 31;
  const float* src = ws + O_H1 + (size_t)b*19200;
  float s = 0.f, sq = 0.f;
  for(int nj = half*75; nj < half*75 + 75; nj++){
    float v = src[(h*150 + nj)*32 + o];
    s += v; sq += v*v;
  }
  __shared__ float ls[256], lq[256];
  ls[t] = s; lq[t] = sq; __syncthreads();
  if(t < 128){
    ws[O_P1 + b*256 + p]       = ls[t] + ls[t+128];
    ws[O_P1 + b*256 + 128 + p] = lq[t] + lq[t+128];
  }
}

__global__ void k_bn1f(const float* g, const float* be, float* __restrict__ ws){
  int t = threadIdx.x;
  if(t < 128){
    float s = 0.f, sq = 0.f;
    for(int b = 0; b < 64; b++){ s += ws[O_P1 + b*256 + t]; sq += ws[O_P1 + b*256 + 128 + t]; }
    float mean = s * (1.f/9600.f), var = sq * (1.f/9600.f) - mean*mean;
    float sc = g[t] * rsqrtf(var + 1e-5f);
    ws[O_BN1S+t] = sc; ws[O_BN1T+t] = be[t] - sc*mean;
  }
}

// ---------------- K9: BN1+relu then conv2 (1x3) + BN2 partials ----------------
__global__ __launch_bounds__(256) void k_conv2(const float* __restrict__ g2w,
                                               const float* __restrict__ g2bias,
                                               float* __restrict__ ws){
  int h = blockIdx.x, b = blockIdx.y;
  __shared__ float hl[150][33];
  __shared__ float w2l[3072];                 // [(i*3+t)*32+o]
  __shared__ float rs[8][32], rq[8][32];
  int t = threadIdx.x;
  const float* h1p = ws + O_H1 + (size_t)(b*4 + h)*4800;
  for(int i = t; i < 4800; i += 256){
    int nj = i >> 5, ii = i & 31;
    hl[nj][ii] = fmaxf(ws[O_BN1S + h*32 + ii]*h1p[i] + ws[O_BN1T + h*32 + ii], 0.f);
  }
  for(int i = t; i < 3072; i += 256){
    int o = i / 96, r = i % 96, ii = r / 3, tt = r % 3;
    w2l[(ii*3 + tt)*32 + o] = g2w[(size_t)h*3072 + i];
  }
  __syncthreads();
  int o = t & 31, ng = t >> 5;
  float bias = g2bias[h*32 + o];
  float s = 0.f, sq = 0.f;
  for(int n = ng; n < 50; n += 8){
    float acc = 0.f;
    for(int t3 = 0; t3 < 3; t3++){
      const float* hr = hl[n*3 + t3];
      #pragma unroll
      for(int ii = 0; ii < 32; ii++) acc += hr[ii] * w2l[(ii*3 + t3)*32 + o];
    }
    acc += bias;
    ws[O_H2 + ((size_t)(b*4 + h)*50 + n)*32 + o] = acc;
    s += acc; sq += acc*acc;
  }
  rs[ng][o] = s; rq[ng][o] = sq; __syncthreads();
  if(t < 32){
    float S = 0.f, Q = 0.f;
    for(int g2 = 0; g2 < 8; g2++){ S += rs[g2][t]; Q += rq[g2][t]; }
    ws[O_P2 + (b*4 + h)*64 + t]      = S;
    ws[O_P2 + (b*4 + h)*64 + 32 + t] = Q;
  }
}

__global__ void k_bn2f(const float* g, const float* be, float* __restrict__ ws){
  int t = threadIdx.x;
  if(t < 128){
    int h = t >> 5, o = t & 31;
    float s = 0.f, sq = 0.f;
    for(int b = 0; b < 64; b++){
      s  += ws[O_P2 + (size_t)(b*4 + h)*64 + o];
      sq += ws[O_P2 + (size_t)(b*4 + h)*64 + 32 + o];
    }
    float mean = s * (1.f/3200.f), var = sq * (1.f/3200.f) - mean*mean;
    float sc = g[t] * rsqrtf(var + 1e-5f);
    ws[O_BN2S+t] = sc; ws[O_BN2T+t] = be[t] - sc*mean;
  }
}

// ---------------- K10: tiny attention + assemble cat [b][256][50] ----------------
__global__ __launch_bounds__(256) void k_attn(float* __restrict__ ws){
  int h = blockIdx.x, b = blockIdx.y;
  __shared__ float qtl[50][33], ktl[50][33], vtl[50][33], al[50][52];
  int t = threadIdx.x;
  size_t base = (size_t)(b*4 + h)*1600;
  for(int i = t; i < 1600; i += 256){
    int n = i >> 5, d = i & 31;
    qtl[n][d] = ws[O_QT + base + i];
    ktl[n][d] = ws[O_KT + base + i];
    vtl[n][d] = ws[O_VT + base + i];
  }
  __syncthreads();
  for(int i = t; i < 2500; i += 256){
    int n = i / 50, m = i % 50;
    float s = 0.f;
    for(int d = 0; d < 32; d++) s += qtl[n][d]*ktl[m][d];
    al[n][m] = s * 0.17677669529663687f;      // 32^-0.5
  }
  __syncthreads();
  if(t < 50){
    float m = -INFINITY;
    for(int j = 0; j < 50; j++) m = fmaxf(m, al[t][j]);
    float s = 0.f;
    for(int j = 0; j < 50; j++){ float e = expf(al[t][j] - m); al[t][j] = e; s += e; }
    float inv = 1.f/s;
    for(int j = 0; j < 50; j++) al[t][j] *= inv;
  }
  __syncthreads();
  for(int i = t; i < 1600; i += 256){
    int n = i >> 5, d = i & 31;
    float gacc = 0.f;
    for(int m = 0; m < 50; m++) gacc += al[n][m]*vtl[m][d];
    ws[O_CAT + ((size_t)b*256 + h*64 + 32 + d)*50 + n] = gacc;
    float l = fmaxf(ws[O_BN2S + h*32 + d]*ws[O_H2 + ((size_t)(b*4 + h)*50 + n)*32 + d] + ws[O_BN2T + h*32 + d], 0.f);
    ws[O_CAT + ((size_t)b*256 + h*64 + d)*50 + n] = l;
  }
}

// ---------------- K11: res = pres_w@cat + pres_b ; pres2 = proj_w@res ----------------
__global__ __launch_bounds__(256) void k_res(float* __restrict__ ws){
  int b = blockIdx.x;
  __shared__ float resl[128][52];
  int t = threadIdx.x;
  int w = __builtin_amdgcn_readfirstlane(t >> 7);   // 0/1
  int o = t & 127;
  int cb = w * 26;                                  // cols 0..25 / 26..51 (50,51 garbage, guarded)
  float acc[26];
  #pragma unroll
  for(int i = 0; i < 26; i++) acc[i] = 0.f;
  const float* pw  = ws + O_PRESWT;
  const float* cat = ws + O_CAT + (size_t)b*12800;
  for(int k = 0; k < 256; k++){
    float wv = pw[k*128 + o];
    const float* cr = cat + k*50 + cb;
    #pragma unroll
    for(int i = 0; i < 26; i++) acc[i] += cr[i] * wv;
  }
  float pb = ws[O_PRESB + o];
  #pragma unroll
  for(int i = 0; i < 26; i++) resl[o][cb+i] = acc[i] + pb;
  __syncthreads();
  const float* qw = ws + O_PROJWT;
  #pragma unroll
  for(int i = 0; i < 26; i++) acc[i] = 0.f;
  for(int k = 0; k < 128; k++){
    float wv = qw[k*128 + o];
    #pragma unroll
    for(int i = 0; i < 26; i++) acc[i] += resl[k][cb+i] * wv;
  }
  float* out = ws + O_PRES2 + (size_t)b*6400 + (size_t)o*50;
  #pragma unroll
  for(int i = 0; i < 26; i++){
    int c = cb + i;
    if(c < 50) out[c] = acc[i];
  }
}

// ---------------- K12: out = pres2 @ softmax_cl(embed2) + proj_b ----------------
__global__ __launch_bounds__(256) void k_out(const float* __restrict__ projb,
                                             float* __restrict__ ws,
                                             float* __restrict__ out){
  int b = blockIdx.y, n0 = blockIdx.x * 64;
  __shared__ float sl[50][64];
  __shared__ float p2l[128][52];
  int t = threadIdx.x;
  for(int i = t; i < 3200; i += 256){
    int c = i >> 6, j = i & 63, n = n0 + j;
    sl[c][j] = (n < 4000) ? ws[O_E2 + ((size_t)b*50 + c)*4000 + n] : 0.f;
  }
  for(int i = t; i < 6656; i += 256){
    int o = i / 52, c = i % 52;
    p2l[o][c] = (c < 50) ? ws[O_PRES2 + (size_t)b*6400 + o*50 + c] : 0.f;
  }
  __syncthreads();
  if(t < 64){
    int j = t;
    float m = -INFINITY;
    for(int c = 0; c < 50; c++) m = fmaxf(m, sl[c][j]);
    float s = 0.f;
    for(int c = 0; c < 50; c++){ float e = expf(sl[c][j] - m); sl[c][j] = e; s += e; }
    float inv = 1.f/s;
    for(int c = 0; c < 50; c++) sl[c][j] *= inv;
  }
  __syncthreads();
  int w = __builtin_amdgcn_readfirstlane(t >> 6);
  int j = t & 63;
  int ob = w * 32;
  float acc[32];
  #pragma unroll
  for(int i = 0; i < 32; i++) acc[i] = 0.f;
  for(int c = 0; c < 50; c++){
    float s = sl[c][j];
    #pragma unroll
    for(int i = 0; i < 32; i++) acc[i] += p2l[ob+i][c] * s;
  }
  int n = n0 + j;
  if(n < 4000){
    #pragma unroll
    for(int i = 0; i < 32; i++){
      out[((size_t)(b*128 + ob + i))*4000 + n] = acc[i] + projb[ob+i];
    }
  }
}

extern "C" void kernel_launch(void* const* d_in, const int* in_sizes, int n_in,
                              void* d_out, int out_size, void* d_ws, size_t ws_size,
                              hipStream_t stream){
  (void)in_sizes; (void)n_in; (void)out_size; (void)ws_size;
  const float* x      = (const float*)d_in[0];
  const float* wg1    = (const float*)d_in[1];
  const float* bg1    = (const float*)d_in[2];
  const float* g1g    = (const float*)d_in[3];
  const float* g1b    = (const float*)d_in[4];
  const float* wg2    = (const float*)d_in[5];
  const float* bg2    = (const float*)d_in[6];
  const float* g2g    = (const float*)d_in[7];
  const float* g2b    = (const float*)d_in[8];
  const float* qkvw   = (const float*)d_in[9];
  const float* qkvb   = (const float*)d_in[10];
  const float* qkv1w  = (const float*)d_in[11];
  const float* qkv1b  = (const float*)d_in[12];
  const float* gc1w   = (const float*)d_in[13];
  const float* gc1bias= (const float*)d_in[14];
  const float* gc1g   = (const float*)d_in[15];
  const float* gc1be  = (const float*)d_in[16];
  const float* gc2w   = (const float*)d_in[17];
  const float* gc2bias= (const float*)d_in[18];
  const float* gc2g   = (const float*)d_in[19];
  const float* gc2be  = (const float*)d_in[20];
  const float* presw  = (const float*)d_in[21];
  const float* presb  = (const float*)d_in[22];
  const float* projw  = (const float*)d_in[23];
  const float* projb  = (const float*)d_in[24];
  float* ws = (float*)d_ws;
  float* out = (float*)d_out;

  k_rowstats<<<8192, 256, 0, stream>>>(x, ws);
  k_prep<<<1, 256, 0, stream>>>(g1g, g1b, g2g, g2b, wg1, bg1, wg2, bg2, presw, presb, projw, ws);
  k_embed<<<dim3(63, 64), 256, 0, stream>>>(x, ws);
  k_rowsm<<<3200, 256, 0, stream>>>(ws);
  k_cxp<<<dim3(8, 64), 256, 0, stream>>>(x, ws);
  k_cxsum<<<1600, 256, 0, stream>>>(ws);
  k_qkv<<<dim3(8, 64), 256, 0, stream>>>(qkvw, qkvb, qkv1w, qkv1b, ws);
  k_knn<<<dim3(4, 64), 256, 0, stream>>>(gc1w, gc1bias, ws);
  k_bn1p<<<64, 256, 0, stream>>>(ws);
  k_bn1f<<<1, 128, 0, stream>>>(gc1g, gc1be, ws);
  k_conv2<<<dim3(4, 64), 256, 0, stream>>>(gc2w, gc2bias, ws);
  k_bn2f<<<1, 128, 0, stream>>>(gc2g, gc2be, ws);
  k_attn<<<dim3(4, 64), 256, 0, stream>>>(ws);
  k_res<<<64, 256, 0, stream>>>(ws);
  k_out<<<dim3(63, 64), 256, 0, stream>>>(projb, ws, out);
}

// Round 3
// 974.056 us; speedup vs baseline: 1.1252x; 1.1252x over previous
//
#include <hip/hip_runtime.h>
#include <cstddef>

// EfficientAttention pipeline, MI355X. fp32 throughout.
// B=64, DIM=128, N=4000, H=4, DH=32, CL=50, K=9.
// R3: scalar-load (s_load) restructure of the 4 big GEMM-ish kernels; the small
// wave-uniform operand moved to global (scalar cache) instead of LDS broadcast.

// ---- workspace offsets (in floats) ----
constexpr size_t O_MU    = 0;
constexpr size_t O_RINV  = O_MU    + 8192;
constexpr size_t O_RATIO = O_RINV  + 8192;
constexpr size_t O_A1    = O_RATIO + 8192;
constexpr size_t O_B1    = O_A1    + 128;
constexpr size_t O_A2    = O_B1    + 128;
constexpr size_t O_B2    = O_A2    + 128;
constexpr size_t O_W1T   = O_B2    + 128;        // [c][64] (50 used)
constexpr size_t O_W2T   = O_W1T   + 8192;
constexpr size_t O_BG1   = O_W2T   + 8192;
constexpr size_t O_BG2   = O_BG1   + 64;
constexpr size_t O_PRESWT= O_BG2   + 64;         // 256x128 pres_w^T [k][o]
constexpr size_t O_PROJWT= O_PRESWT+ 32768;      // 128x128 proj_w^T [d][o]
constexpr size_t O_PRESB = O_PROJWT+ 16384;      // 128
constexpr size_t O_VPROJ = O_PRESB + 128;        // 128   v = projw@pres_b
constexpr size_t O_MT    = O_VPROJ + 128;        // 256x128  M^T [k][o], M=projw@presw
constexpr size_t O_E1    = O_MT    + 32768;      // 64*50*4000
constexpr size_t O_E2    = O_E1    + 12800000;   // 64*50*4000
constexpr size_t O_RMAX  = O_E2    + 12800000;   // 3200
constexpr size_t O_RSINV = O_RMAX  + 3200;       // 3200
constexpr size_t O_CXP   = O_RSINV + 3200;       // 8*64*128*50
constexpr size_t O_CX    = O_CXP   + 3276800;    // 64*128*50 [b][d][c]
constexpr size_t O_XT    = O_CX    + 409600;     // 64*4*50*32 [b][h][c][d]
constexpr size_t O_QT    = O_XT    + 409600;
constexpr size_t O_KT    = O_QT    + 409600;
constexpr size_t O_VT    = O_KT    + 409600;
constexpr size_t O_H1    = O_VT    + 409600;     // 64*4*150*32
constexpr size_t O_P1    = O_H1    + 1228800;    // 64*256
constexpr size_t O_BN1S  = O_P1    + 16384;
constexpr size_t O_BN1T  = O_BN1S  + 128;
constexpr size_t O_H2    = O_BN1T  + 128;        // 64*4*50*32
constexpr size_t O_P2    = O_H2    + 409600;     // 256*64
constexpr size_t O_BN2S  = O_P2    + 16384;
constexpr size_t O_BN2T  = O_BN2S  + 128;
constexpr size_t O_CAT   = O_BN2T  + 128;        // 64*256*50 [b][ch][n]
constexpr size_t O_PRES2 = O_CAT   + 819200;     // 64*50*128 [b][c][o]
constexpr size_t O_END   = O_PRES2 + 409600;
// P^T (softmaxed S1 transposed), [b_local][n][52]
constexpr size_t O_PT_FULL = O_END;              // full: 64*4000*52 = 13312000
constexpr size_t PT_FULL_SZ = 13312000;
// quarter fallback: reuse XT.. region (written only after cxp completes)
constexpr size_t O_PT_Q  = O_XT;                 // 16*4000*52 = 3328000 fits before use

// ---------------- K1: per-(b,c) instance-norm stats over n=4000 ----------------
__global__ __launch_bounds__(256) void k_rowstats(const float* __restrict__ x,
                                                  float* __restrict__ ws){
  int row = blockIdx.x;                       // b*128+c
  const float4* xr = (const float4*)(x + (size_t)row * 4000);
  float s = 0.f, sq = 0.f;
  for(int i = threadIdx.x; i < 1000; i += 256){
    float4 v = xr[i];
    s  += v.x + v.y + v.z + v.w;
    sq += v.x*v.x + v.y*v.y + v.z*v.z + v.w*v.w;
  }
  __shared__ float ls[256], lq[256];
  ls[threadIdx.x] = s; lq[threadIdx.x] = sq; __syncthreads();
  for(int st = 128; st > 0; st >>= 1){
    if(threadIdx.x < st){ ls[threadIdx.x] += ls[threadIdx.x+st]; lq[threadIdx.x] += lq[threadIdx.x+st]; }
    __syncthreads();
  }
  if(threadIdx.x == 0){
    float mean = ls[0] * (1.f/4000.f);
    float var  = lq[0] * (1.f/4000.f) - mean*mean;
    ws[O_MU   + row] = mean;
    ws[O_RINV + row] = rsqrtf(var + 1e-3f);
    ws[O_RATIO+ row] = var / (var + 1e-3f);
  }
}

// ---------------- K2: BN stats (mu2==0 exactly) + weight prep + vproj ----------------
__global__ void k_prep(const float* g1g, const float* g1b,
                       const float* g2g, const float* g2b,
                       const float* wg1, const float* bg1,
                       const float* wg2, const float* bg2,
                       const float* presw, const float* presb,
                       const float* projw,
                       float* __restrict__ ws){
  int t = threadIdx.x;
  if(t < 128){
    float s = 0.f;
    for(int b = 0; b < 64; b++) s += ws[O_RATIO + b*128 + t];
    float var2 = s * (1.f/64.f);
    float inv2 = rsqrtf(var2 + 1e-5f);
    ws[O_A1+t] = g1g[t] * inv2;  ws[O_B1+t] = g1b[t];
    ws[O_A2+t] = g2g[t] * inv2;  ws[O_B2+t] = g2b[t];
  }
  for(int i = t; i < 8192; i += 256){
    int c = i >> 6, cl = i & 63;
    ws[O_W1T+i] = (cl < 50) ? wg1[cl*128 + c] : 0.f;
    ws[O_W2T+i] = (cl < 50) ? wg2[cl*128 + c] : 0.f;
  }
  if(t < 50){ ws[O_BG1+t] = bg1[t]; ws[O_BG2+t] = bg2[t]; }
  for(int i = t; i < 32768; i += 256){ int o = i & 127, k = i >> 7; ws[O_PRESWT+i] = presw[o*256 + k]; }
  for(int i = t; i < 16384; i += 256){ int o = i & 127, k = i >> 7; ws[O_PROJWT+i] = projw[o*128 + k]; }
  if(t < 128) ws[O_PRESB+t] = presb[t];
  __syncthreads();
  if(t < 128){
    float v = 0.f;
    for(int d = 0; d < 128; d++) v += ws[O_PROJWT + d*128 + t] * presb[d];
    ws[O_VPROJ + t] = v;
  }
}

// ---------------- K2b: M^T[k][o] = sum_d projw^T[d][o] * presw[d][k] ----------------
__global__ __launch_bounds__(256) void k_mprep(const float* __restrict__ presw,
                                               float* __restrict__ ws){
  int kk = blockIdx.x*2 + (threadIdx.x >> 7);   // 0..255
  int o  = threadIdx.x & 127;
  int ku = __builtin_amdgcn_readfirstlane(kk);
  float acc = 0.f;
  for(int d = 0; d < 128; d++)
    acc += ws[O_PROJWT + d*128 + o] * presw[d*256 + ku];
  ws[O_MT + (size_t)kk*128 + o] = acc;
}

// ---------------- K3: embed1/embed2 = Wg @ relu(affine(xin)) ----------------
__global__ __launch_bounds__(256) void k_embed(const float* __restrict__ x,
                                               float* __restrict__ ws){
  int b = blockIdx.y, n0 = blockIdx.x * 64;
  __shared__ float xin[8192];        // [c][64], 32 KB
  __shared__ float2 coef[2][128];    // (a, b') per embed per c
  int t = threadIdx.x;
  if(t < 128){
    float mu = ws[O_MU + b*128 + t], ri = ws[O_RINV + b*128 + t];
    float a1 = ws[O_A1+t]*ri, a2 = ws[O_A2+t]*ri;
    coef[0][t] = make_float2(a1, ws[O_B1+t] - a1*mu);
    coef[1][t] = make_float2(a2, ws[O_B2+t] - a2*mu);
  }
  for(int i = t; i < 8192; i += 256){
    int c = i >> 6, j = i & 63, n = n0 + j;
    xin[i] = (n < 4000) ? x[(size_t)(b*128 + c)*4000 + n] : 0.f;
  }
  __syncthreads();
  int w = t >> 6, lane = t & 63;
  int g = w >> 1, clb = (w & 1) * 25;
  int wbase = __builtin_amdgcn_readfirstlane((int)(g ? O_W2T : O_W1T) + clb);
  float acc[25];
  #pragma unroll
  for(int i = 0; i < 25; i++) acc[i] = 0.f;
  #pragma unroll 2
  for(int c = 0; c < 128; c++){
    float2 ab = coef[g][c];
    float rv = fmaxf(ab.x * xin[c*64 + lane] + ab.y, 0.f);
    const float* wr = ws + wbase + c*64;
    #pragma unroll
    for(int i = 0; i < 25; i++) acc[i] += wr[i] * rv;
  }
  int n = n0 + lane;
  if(n < 4000){
    const float* bgp = ws + (g ? O_BG2 : O_BG1) + clb;
    float* e = ws + (g ? O_E2 : O_E1) + (size_t)b*200000 + n;
    #pragma unroll
    for(int i = 0; i < 25; i++) e[(size_t)(clb+i)*4000] = acc[i] + bgp[i];
  }
}

// ---------------- K4: softmax-over-n row stats for embed1 ----------------
__global__ __launch_bounds__(256) void k_rowsm(float* __restrict__ ws){
  int row = blockIdx.x;                 // b*50+cl
  const float* e = ws + O_E1 + (size_t)row * 4000;
  int t = threadIdx.x;
  float vals[16];
  float m = -INFINITY;
  #pragma unroll
  for(int i = 0; i < 16; i++){
    int n = t + i*256;
    float v = (n < 4000) ? e[n] : -INFINITY;
    vals[i] = v; m = fmaxf(m, v);
  }
  __shared__ float red[256];
  red[t] = m; __syncthreads();
  for(int st = 128; st > 0; st >>= 1){ if(t < st) red[t] = fmaxf(red[t], red[t+st]); __syncthreads(); }
  float M = red[0];
  __syncthreads();
  float s = 0.f;
  #pragma unroll
  for(int i = 0; i < 16; i++) s += expf(vals[i] - M);
  red[t] = s; __syncthreads();
  for(int st = 128; st > 0; st >>= 1){ if(t < st) red[t] += red[t+st]; __syncthreads(); }
  if(t == 0){ ws[O_RMAX+row] = M; ws[O_RSINV+row] = 1.f / red[0]; }
}

// ---------------- K4b: P^T[b_local][n][52] = softmax(E1) transposed ----------------
__global__ __launch_bounds__(256) void k_psm(float* __restrict__ ws, int b0, int pt_off){
  int bl = blockIdx.y, b = b0 + bl, n0 = blockIdx.x * 128;
  __shared__ float pT[128][53];
  int t = threadIdx.x;
  for(int i = t; i < 6400; i += 256){
    int r = i >> 7, j = i & 127;
    int n = n0 + j;
    float v = 0.f;
    if(n < 4000){
      int row = b*50 + r;
      v = expf(ws[O_E1 + (size_t)row*4000 + n] - ws[O_RMAX+row]) * ws[O_RSINV+row];
    }
    pT[j][r] = v;
  }
  if(t < 128){ pT[t][50] = 0.f; pT[t][51] = 0.f; }
  __syncthreads();
  for(int i = t; i < 6656; i += 256){
    int n = i / 52, c = i % 52;
    if(n0 + n < 4000)
      ws[(size_t)pt_off + ((size_t)bl*4000 + n0 + n)*52 + c] = pT[n][c];
  }
}

// ---------------- K5: cluster_x partials via scalar P^T loads ----------------
__global__ __launch_bounds__(256) void k_cxp(const float* __restrict__ x,
                                             float* __restrict__ ws, int b0, int pt_off){
  int bl = blockIdx.y, b = b0 + bl, ch = blockIdx.x;  // 8 chunks of 500 points
  __shared__ float xT[64][129];
  int t = threadIdx.x;
  int w = t >> 6, lane = t & 63;
  int d  = lane + (w & 1)*64;
  int cb = (w >> 1) * 26;                              // 0 or 26 (cols 50/51 pad)
  int pbase = __builtin_amdgcn_readfirstlane(pt_off + cb);
  float acc[26];
  #pragma unroll
  for(int i = 0; i < 26; i++) acc[i] = 0.f;
  int nbase = ch * 500;
  for(int tile = 0; tile < 8; tile++){
    int n0  = nbase + tile*64;
    int lim = min(64, nbase + 500 - n0);
    __syncthreads();
    for(int i = t; i < 8192; i += 256){
      int dd = i >> 6, j = i & 63;
      xT[j][dd] = (j < lim) ? x[(size_t)(b*128 + dd)*4000 + n0 + j] : 0.f;
    }
    __syncthreads();
    for(int j = 0; j < lim; j++){
      float xv = xT[j][d];
      const float* pr = ws + pbase + (size_t)(bl*4000 + n0 + j)*52;
      #pragma unroll
      for(int i = 0; i < 26; i++) acc[i] += pr[i] * xv;
    }
  }
  float* o = ws + O_CXP + ((size_t)(ch*64 + b)*128 + d)*50;
  #pragma unroll
  for(int i = 0; i < 26; i++){
    int c = cb + i;
    if(c < 50) o[c] = acc[i];
  }
}

__global__ void k_cxsum(float* __restrict__ ws){
  int idx = blockIdx.x*256 + threadIdx.x;     // 409600
  if(idx < 409600){
    float s = 0.f;
    for(int ch = 0; ch < 8; ch++) s += ws[O_CXP + (size_t)ch*409600 + idx];
    ws[O_CX + idx] = s;
  }
}

// ---------------- K6: qkv + qkv1 projections ----------------
__global__ __launch_bounds__(256) void k_qkv(const float* __restrict__ qw,
                                             const float* __restrict__ qb,
                                             const float* __restrict__ q1w,
                                             const float* __restrict__ q1b,
                                             float* __restrict__ ws){
  int b = blockIdx.y, rt = blockIdx.x;        // 8 row-tiles of 64
  __shared__ float wl[128][65];
  int t = threadIdx.x;
  for(int i = t; i < 8192; i += 256){
    int k = i & 127, rl = i >> 7, row = rt*64 + rl;
    wl[k][rl] = (row < 128) ? qw[row*128 + k] : q1w[(row-128)*128 + k];
  }
  __syncthreads();
  int w  = t >> 6;
  int rl = t & 63;
  int cb = w * 13;
  int cxb = __builtin_amdgcn_readfirstlane((int)O_CX + b*6400 + cb);
  float acc[13];
  #pragma unroll
  for(int i = 0; i < 13; i++) acc[i] = 0.f;
  for(int k = 0; k < 128; k++){
    float wv = wl[k][rl];
    const float* cr = ws + cxb + k*50;
    #pragma unroll
    for(int i = 0; i < 13; i++) acc[i] += cr[i] * wv;
  }
  int row = rt*64 + rl;
  size_t base; float bias;
  if(row < 128){
    int h = row >> 5;
    bias = qb[row];
    base = O_XT + (size_t)(b*4 + h)*1600 + (row & 31);
  }else{
    int r2 = row - 128, h = r2/96, j = r2%96, kind = j >> 5, dd = j & 31;
    bias = q1b[r2];
    base = (kind==0 ? O_QT : kind==1 ? O_KT : O_VT) + (size_t)(b*4 + h)*1600 + dd;
  }
  #pragma unroll
  for(int i = 0; i < 13; i++){
    int c = cb + i;
    if(c < 50) ws[base + (size_t)c*32] = acc[i] + bias;
  }
}

// ---------------- K7: knn (top-9, jax tie order) + edge + conv1 ----------------
__global__ __launch_bounds__(256) void k_knn(const float* __restrict__ g1w,
                                             const float* __restrict__ g1bias,
                                             float* __restrict__ ws){
  int h = blockIdx.x, b = blockIdx.y;
  __shared__ float xtl[50][33];
  __shared__ float pdl[50][52];
  __shared__ float sql[50];
  __shared__ int   idxl[50][9];
  __shared__ float w1l[6144];                 // [(i*3+t)*32+o]
  int t = threadIdx.x;
  const float* xtg = ws + O_XT + (size_t)(b*4 + h)*1600;
  for(int i = t; i < 1600; i += 256) xtl[i >> 5][i & 31] = xtg[i];
  for(int i = t; i < 6144; i += 256){
    int o = i / 192, r = i % 192, ii = r / 3, tt = r % 3;
    w1l[(ii*3 + tt)*32 + o] = g1w[(size_t)h*6144 + i];
  }
  __syncthreads();
  if(t < 50){
    float s = 0.f;
    for(int d = 0; d < 32; d++){ float v = xtl[t][d]; s += v*v; }
    sql[t] = s;
  }
  __syncthreads();
  for(int i = t; i < 2500; i += 256){
    int n = i / 50, m = i % 50;
    float s = 0.f;
    for(int d = 0; d < 32; d++) s += xtl[n][d]*xtl[m][d];
    pdl[n][m] = 2.f*s - sql[n] - sql[m];
  }
  __syncthreads();
  if(t < 50){
    float pv = INFINITY; int pi = -1;
    for(int k = 0; k < 9; k++){
      float bv = -INFINITY; int bi = 1000;
      for(int m = 0; m < 50; m++){
        float v = pdl[t][m];
        bool elig = (v < pv) || (v == pv && m > pi);
        if(elig && (v > bv || (v == bv && m < bi))){ bv = v; bi = m; }
      }
      idxl[t][k] = bi; pv = bv; pi = bi;
    }
  }
  __syncthreads();
  if(t < 150){
    int n = t / 3, jw = t % 3;
    float acc[32];
    #pragma unroll
    for(int o = 0; o < 32; o++) acc[o] = 0.f;
    for(int t3 = 0; t3 < 3; t3++){
      int kx = idxl[n][jw*3 + t3];
      for(int ii = 0; ii < 32; ii++){
        float c0 = xtl[n][ii];
        float c1 = c0 - xtl[kx][ii];
        const float* wr0 = w1l + (ii*3 + t3)*32;
        const float* wr1 = w1l + ((ii+32)*3 + t3)*32;
        #pragma unroll
        for(int o = 0; o < 32; o++) acc[o] += c0*wr0[o] + c1*wr1[o];
      }
    }
    float* out = ws + O_H1 + ((size_t)(b*4 + h)*150 + n*3 + jw)*32;
    #pragma unroll
    for(int o = 0; o < 32; o++) out[o] = acc[o] + g1bias[h*32 + o];
  }
}

// ---------------- K8: BN1 stats ----------------
__global__ void k_bn1p(float* __restrict__ ws){
  int b = blockIdx.x, t = threadIdx.x;
  int p = t & 127, half = t >> 7;
  int h = p >> 5, o = p & 31;
  const float* src = ws + O_H1 + (size_t)b*19200;
  float s = 0.f, sq = 0.f;
  for(int nj = half*75; nj < half*75 + 75; nj++){
    float v = src[(h*150 + nj)*32 + o];
    s += v; sq += v*v;
  }
  __shared__ float ls[256], lq[256];
  ls[t] = s; lq[t] = sq; __syncthreads();
  if(t < 128){
    ws[O_P1 + b*256 + p]       = ls[t] + ls[t+128];
    ws[O_P1 + b*256 + 128 + p] = lq[t] + lq[t+128];
  }
}

__global__ void k_bn1f(const float* g, const float* be, float* __restrict__ ws){
  int t = threadIdx.x;
  if(t < 128){
    float s = 0.f, sq = 0.f;
    for(int b = 0; b < 64; b++){ s += ws[O_P1 + b*256 + t]; sq += ws[O_P1 + b*256 + 128 + t]; }
    float mean = s * (1.f/9600.f), var = sq * (1.f/9600.f) - mean*mean;
    float sc = g[t] * rsqrtf(var + 1e-5f);
    ws[O_BN1S+t] = sc; ws[O_BN1T+t] = be[t] - sc*mean;
  }
}

// ---------------- K9: BN1+relu then conv2 (1x3) + BN2 partials ----------------
__global__ __launch_bounds__(256) void k_conv2(const float* __restrict__ g2w,
                                               const float* __restrict__ g2bias,
                                               float* __restrict__ ws){
  int h = blockIdx.x, b = blockIdx.y;
  __shared__ float hl[150][33];
  __shared__ float w2l[3072];
  __shared__ float rs[8][32], rq[8][32];
  int t = threadIdx.x;
  const float* h1p = ws + O_H1 + (size_t)(b*4 + h)*4800;
  for(int i = t; i < 4800; i += 256){
    int nj = i >> 5, ii = i & 31;
    hl[nj][ii] = fmaxf(ws[O_BN1S + h*32 + ii]*h1p[i] + ws[O_BN1T + h*32 + ii], 0.f);
  }
  for(int i = t; i < 3072; i += 256){
    int o = i / 96, r = i % 96, ii = r / 3, tt = r % 3;
    w2l[(ii*3 + tt)*32 + o] = g2w[(size_t)h*3072 + i];
  }
  __syncthreads();
  int o = t & 31, ng = t >> 5;
  float bias = g2bias[h*32 + o];
  float s = 0.f, sq = 0.f;
  for(int n = ng; n < 50; n += 8){
    float acc = 0.f;
    for(int t3 = 0; t3 < 3; t3++){
      const float* hr = hl[n*3 + t3];
      #pragma unroll
      for(int ii = 0; ii < 32; ii++) acc += hr[ii] * w2l[(ii*3 + t3)*32 + o];
    }
    acc += bias;
    ws[O_H2 + ((size_t)(b*4 + h)*50 + n)*32 + o] = acc;
    s += acc; sq += acc*acc;
  }
  rs[ng][o] = s; rq[ng][o] = sq; __syncthreads();
  if(t < 32){
    float S = 0.f, Q = 0.f;
    for(int g2 = 0; g2 < 8; g2++){ S += rs[g2][t]; Q += rq[g2][t]; }
    ws[O_P2 + (b*4 + h)*64 + t]      = S;
    ws[O_P2 + (b*4 + h)*64 + 32 + t] = Q;
  }
}

__global__ void k_bn2f(const float* g, const float* be, float* __restrict__ ws){
  int t = threadIdx.x;
  if(t < 128){
    int h = t >> 5, o = t & 31;
    float s = 0.f, sq = 0.f;
    for(int b = 0; b < 64; b++){
      s  += ws[O_P2 + (size_t)(b*4 + h)*64 + o];
      sq += ws[O_P2 + (size_t)(b*4 + h)*64 + 32 + o];
    }
    float mean = s * (1.f/3200.f), var = sq * (1.f/3200.f) - mean*mean;
    float sc = g[t] * rsqrtf(var + 1e-5f);
    ws[O_BN2S+t] = sc; ws[O_BN2T+t] = be[t] - sc*mean;
  }
}

// ---------------- K10: tiny attention + assemble cat [b][256][50] ----------------
__global__ __launch_bounds__(256) void k_attn(float* __restrict__ ws){
  int h = blockIdx.x, b = blockIdx.y;
  __shared__ float qtl[50][33], ktl[50][33], vtl[50][33], al[50][52];
  int t = threadIdx.x;
  size_t base = (size_t)(b*4 + h)*1600;
  for(int i = t; i < 1600; i += 256){
    int n = i >> 5, d = i & 31;
    qtl[n][d] = ws[O_QT + base + i];
    ktl[n][d] = ws[O_KT + base + i];
    vtl[n][d] = ws[O_VT + base + i];
  }
  __syncthreads();
  for(int i = t; i < 2500; i += 256){
    int n = i / 50, m = i % 50;
    float s = 0.f;
    for(int d = 0; d < 32; d++) s += qtl[n][d]*ktl[m][d];
    al[n][m] = s * 0.17677669529663687f;
  }
  __syncthreads();
  if(t < 50){
    float m = -INFINITY;
    for(int j = 0; j < 50; j++) m = fmaxf(m, al[t][j]);
    float s = 0.f;
    for(int j = 0; j < 50; j++){ float e = expf(al[t][j] - m); al[t][j] = e; s += e; }
    float inv = 1.f/s;
    for(int j = 0; j < 50; j++) al[t][j] *= inv;
  }
  __syncthreads();
  for(int i = t; i < 1600; i += 256){
    int n = i >> 5, d = i & 31;
    float gacc = 0.f;
    for(int m = 0; m < 50; m++) gacc += al[n][m]*vtl[m][d];
    ws[O_CAT + ((size_t)b*256 + h*64 + 32 + d)*50 + n] = gacc;
    float l = fmaxf(ws[O_BN2S + h*32 + d]*ws[O_H2 + ((size_t)(b*4 + h)*50 + n)*32 + d] + ws[O_BN2T + h*32 + d], 0.f);
    ws[O_CAT + ((size_t)b*256 + h*64 + d)*50 + n] = l;
  }
}

// ---------------- K11: pres2[b][c][o] = (M @ cat)[o][c] + vproj[o] ----------------
__global__ __launch_bounds__(256) void k_res(float* __restrict__ ws){
  int b = blockIdx.x;
  int t = threadIdx.x;
  int w = t >> 7, o = t & 127;
  int cb = w * 26;
  int catb = __builtin_amdgcn_readfirstlane((int)O_CAT + b*12800 + cb);
  float acc[26];
  #pragma unroll
  for(int i = 0; i < 26; i++) acc[i] = 0.f;
  for(int k = 0; k < 256; k++){
    float wv = ws[O_MT + k*128 + o];
    const float* cr = ws + catb + k*50;
    #pragma unroll
    for(int i = 0; i < 26; i++) acc[i] += cr[i] * wv;
  }
  float v = ws[O_VPROJ + o];
  #pragma unroll
  for(int i = 0; i < 26; i++){
    int c = cb + i;
    if(c < 50) ws[O_PRES2 + (size_t)b*6400 + c*128 + o] = acc[i] + v;
  }
}

// ---------------- K12: out = pres2 @ softmax_cl(embed2) + proj_b ----------------
__global__ __launch_bounds__(256) void k_out(const float* __restrict__ projb,
                                             float* __restrict__ ws,
                                             float* __restrict__ out){
  int b = blockIdx.y, n0 = blockIdx.x * 64;
  __shared__ float sl[50][64];
  int t = threadIdx.x;
  for(int i = t; i < 3200; i += 256){
    int c = i >> 6, j = i & 63, n = n0 + j;
    sl[c][j] = (n < 4000) ? ws[O_E2 + ((size_t)b*50 + c)*4000 + n] : 0.f;
  }
  __syncthreads();
  if(t < 64){
    int j = t;
    float m = -INFINITY;
    for(int c = 0; c < 50; c++) m = fmaxf(m, sl[c][j]);
    float s = 0.f;
    for(int c = 0; c < 50; c++){ float e = expf(sl[c][j] - m); sl[c][j] = e; s += e; }
    float inv = 1.f/s;
    for(int c = 0; c < 50; c++) sl[c][j] *= inv;
  }
  __syncthreads();
  int w = t >> 6, j = t & 63;
  int ob = w * 32;
  int pbase = __builtin_amdgcn_readfirstlane((int)O_PRES2 + b*6400 + ob);
  float acc[32];
  #pragma unroll
  for(int i = 0; i < 32; i++) acc[i] = 0.f;
  for(int c = 0; c < 50; c++){
    float s = sl[c][j];
    const float* pr = ws + pbase + c*128;
    #pragma unroll
    for(int i = 0; i < 32; i++) acc[i] += pr[i] * s;
  }
  int n = n0 + j;
  if(n < 4000){
    #pragma unroll
    for(int i = 0; i < 32; i++){
      out[((size_t)(b*128 + ob + i))*4000 + n] = acc[i] + projb[ob+i];
    }
  }
}

extern "C" void kernel_launch(void* const* d_in, const int* in_sizes, int n_in,
                              void* d_out, int out_size, void* d_ws, size_t ws_size,
                              hipStream_t stream){
  (void)in_sizes; (void)n_in; (void)out_size;
  const float* x      = (const float*)d_in[0];
  const float* wg1    = (const float*)d_in[1];
  const float* bg1    = (const float*)d_in[2];
  const float* g1g    = (const float*)d_in[3];
  const float* g1b    = (const float*)d_in[4];
  const float* wg2    = (const float*)d_in[5];
  const float* bg2    = (const float*)d_in[6];
  const float* g2g    = (const float*)d_in[7];
  const float* g2b    = (const float*)d_in[8];
  const float* qkvw   = (const float*)d_in[9];
  const float* qkvb   = (const float*)d_in[10];
  const float* qkv1w  = (const float*)d_in[11];
  const float* qkv1b  = (const float*)d_in[12];
  const float* gc1w   = (const float*)d_in[13];
  const float* gc1bias= (const float*)d_in[14];
  const float* gc1g   = (const float*)d_in[15];
  const float* gc1be  = (const float*)d_in[16];
  const float* gc2w   = (const float*)d_in[17];
  const float* gc2bias= (const float*)d_in[18];
  const float* gc2g   = (const float*)d_in[19];
  const float* gc2be  = (const float*)d_in[20];
  const float* presw  = (const float*)d_in[21];
  const float* presb  = (const float*)d_in[22];
  const float* projw  = (const float*)d_in[23];
  const float* projb  = (const float*)d_in[24];
  float* ws = (float*)d_ws;
  float* out = (float*)d_out;

  k_rowstats<<<8192, 256, 0, stream>>>(x, ws);
  k_prep<<<1, 256, 0, stream>>>(g1g, g1b, g2g, g2b, wg1, bg1, wg2, bg2, presw, presb, projw, ws);
  k_mprep<<<128, 256, 0, stream>>>(presw, ws);
  k_embed<<<dim3(63, 64), 256, 0, stream>>>(x, ws);
  k_rowsm<<<3200, 256, 0, stream>>>(ws);

  bool full = ws_size >= (size_t)(O_PT_FULL + PT_FULL_SZ) * sizeof(float);
  if(full){
    k_psm<<<dim3(32, 64), 256, 0, stream>>>(ws, 0, (int)O_PT_FULL);
    k_cxp<<<dim3(8, 64), 256, 0, stream>>>(x, ws, 0, (int)O_PT_FULL);
  }else{
    for(int q = 0; q < 4; q++){
      k_psm<<<dim3(32, 16), 256, 0, stream>>>(ws, q*16, (int)O_PT_Q);
      k_cxp<<<dim3(8, 16), 256, 0, stream>>>(x, ws, q*16, (int)O_PT_Q);
    }
  }
  k_cxsum<<<1600, 256, 0, stream>>>(ws);
  k_qkv<<<dim3(8, 64), 256, 0, stream>>>(qkvw, qkvb, qkv1w, qkv1b, ws);
  k_knn<<<dim3(4, 64), 256, 0, stream>>>(gc1w, gc1bias, ws);
  k_bn1p<<<64, 256, 0, stream>>>(ws);
  k_bn1f<<<1, 128, 0, stream>>>(gc1g, gc1be, ws);
  k_conv2<<<dim3(4, 64), 256, 0, stream>>>(gc2w, gc2bias, ws);
  k_bn2f<<<1, 128, 0, stream>>>(gc2g, gc2be, ws);
  k_attn<<<dim3(4, 64), 256, 0, stream>>>(ws);
  k_res<<<64, 256, 0, stream>>>(ws);
  k_out<<<dim3(63, 64), 256, 0, stream>>>(projb, ws, out);
}

// Round 4
// 864.564 us; speedup vs baseline: 1.2677x; 1.1266x over previous
//
#include <hip/hip_runtime.h>
#include <cstddef>

// EfficientAttention pipeline, MI355X. fp32 throughout.
// B=64, DIM=128, N=4000, H=4, DH=32, CL=50, K=9.
// R4: fused embed1/embed2/softmax-free cluster_x kernel (exp factorization:
// cx = (x @ exp(E1)^T) / Z, Z from a ones-row). All GEMM-ish kernels use 2D
// register tiles with b128 LDS reads; no s_load chains, no broadcast-b32 storms.

// ---- workspace offsets (in floats) ----
constexpr size_t O_MU    = 0;                   // 8192
constexpr size_t O_RINV  = 8192;                // 8192
constexpr size_t O_RATIO = 16384;               // 8192
constexpr size_t O_A1    = 24576;               // 128
constexpr size_t O_B1    = 24704;
constexpr size_t O_A2    = 24832;
constexpr size_t O_B2    = 24960;
constexpr size_t O_PROJWT= 25088;               // 128x128 proj_w^T [d][o]
constexpr size_t O_VPROJ = 41472;               // 128  projw@pres_b
constexpr size_t O_MT    = 41600;               // 256x128  M^T [k][o], M=projw@presw
constexpr size_t O_E2    = 74368;               // 64*50*4000
constexpr size_t O_UCXP  = 12874368;            // 8*64*132*56 fused GEMM partials
constexpr size_t O_CX    = 16659072;            // 64*128*50 [b][d][c]
constexpr size_t O_XT    = 17068672;            // 64*4*50*32 [b][h][c][d]
constexpr size_t O_QT    = 17478272;
constexpr size_t O_KT    = 17887872;
constexpr size_t O_VT    = 18297472;
constexpr size_t O_H1    = 18707072;            // 64*4*150*32
constexpr size_t O_P1    = 19935872;            // 64*256
constexpr size_t O_BN1S  = 19952256;            // 128
constexpr size_t O_BN1T  = 19952384;
constexpr size_t O_H2    = 19952512;            // 64*4*50*32
constexpr size_t O_P2    = 20362112;            // 256*64
constexpr size_t O_BN2S  = 20378496;
constexpr size_t O_BN2T  = 20378624;
constexpr size_t O_CAT   = 20378752;            // 64*256*50 [b][ch][n]
constexpr size_t O_PRES2 = 21197952;            // 64*50*128 [b][c][o]

// ---------------- K1: per-(b,c) instance-norm stats over n=4000 ----------------
__global__ __launch_bounds__(256) void k_rowstats(const float* __restrict__ x,
                                                  float* __restrict__ ws){
  int row = blockIdx.x;                       // b*128+c
  const float4* xr = (const float4*)(x + (size_t)row * 4000);
  float s = 0.f, sq = 0.f;
  for(int i = threadIdx.x; i < 1000; i += 256){
    float4 v = xr[i];
    s  += v.x + v.y + v.z + v.w;
    sq += v.x*v.x + v.y*v.y + v.z*v.z + v.w*v.w;
  }
  __shared__ float ls[256], lq[256];
  ls[threadIdx.x] = s; lq[threadIdx.x] = sq; __syncthreads();
  for(int st = 128; st > 0; st >>= 1){
    if(threadIdx.x < st){ ls[threadIdx.x] += ls[threadIdx.x+st]; lq[threadIdx.x] += lq[threadIdx.x+st]; }
    __syncthreads();
  }
  if(threadIdx.x == 0){
    float mean = ls[0] * (1.f/4000.f);
    float var  = lq[0] * (1.f/4000.f) - mean*mean;
    ws[O_MU   + row] = mean;
    ws[O_RINV + row] = rsqrtf(var + 1e-3f);
    ws[O_RATIO+ row] = var / (var + 1e-3f);
  }
}

// ---------------- K2: BN stats (mu2==0 exactly) + small weight prep ----------------
__global__ void k_prep(const float* g1g, const float* g1b,
                       const float* g2g, const float* g2b,
                       const float* presb, const float* projw,
                       float* __restrict__ ws){
  int t = threadIdx.x;
  if(t < 128){
    float s = 0.f;
    for(int b = 0; b < 64; b++) s += ws[O_RATIO + b*128 + t];
    float var2 = s * (1.f/64.f);
    float inv2 = rsqrtf(var2 + 1e-5f);
    ws[O_A1+t] = g1g[t] * inv2;  ws[O_B1+t] = g1b[t];
    ws[O_A2+t] = g2g[t] * inv2;  ws[O_B2+t] = g2b[t];
  }
  for(int i = t; i < 16384; i += 256){ int o = i & 127, k = i >> 7; ws[O_PROJWT+i] = projw[o*128 + k]; }
  __syncthreads();
  if(t < 128){
    float v = 0.f;
    for(int d = 0; d < 128; d++) v += ws[O_PROJWT + d*128 + t] * presb[d];
    ws[O_VPROJ + t] = v;
  }
}

// ---------------- K2b: M^T[k][o] = sum_d projw^T[d][o] * presw[d][k] ----------------
__global__ __launch_bounds__(256) void k_mprep(const float* __restrict__ presw,
                                               float* __restrict__ ws){
  int kk2 = blockIdx.x * 2;                   // 128 blocks
  __shared__ float pwc[2][128];
  int t = threadIdx.x;
  { int which = t >> 7, d = t & 127; pwc[which][d] = presw[d*256 + kk2 + which]; }
  __syncthreads();
  int which = t >> 7, o = t & 127;
  float acc = 0.f;
  for(int d = 0; d < 128; d++) acc += ws[O_PROJWT + d*128 + o] * pwc[which][d];
  ws[O_MT + (size_t)(kk2 + which)*128 + o] = acc;
}

// ---------------- K3: fused embed1/embed2 + exp + unnormalized cluster GEMM ----------------
// grid (8 ch, 64 b), 256 thr. Per block: n-chunk of 500 (8 subtiles of 64, last 52).
__global__ __launch_bounds__(256) void k_fused(const float* __restrict__ x,
    const float* __restrict__ wg1, const float* __restrict__ bg1,
    const float* __restrict__ wg2, const float* __restrict__ bg2,
    float* __restrict__ ws){
  int ch = blockIdx.x, b = blockIdx.y;
  __shared__ float lW1[128*56];     // [c][cl], cl padded 56 (zeros)
  __shared__ float lW2[128*56];
  __shared__ float lrv1[128*64];    // [c][j]; after E1: eU overlay [56][64]
  __shared__ float lrv2[128*64];
  __shared__ float lxt [64*132];    // [n][d], d 0..127 + ones-row 128 (+pad)
  __shared__ float ca1[128], cb1[128], ca2[128], cb2[128];
  __shared__ float bg1p[64], bg2p[64];
  int t = threadIdx.x;
  // one-time stages
  if(t < 128){
    float mu = ws[O_MU + b*128 + t], ri = ws[O_RINV + b*128 + t];
    float a1 = ws[O_A1+t]*ri, a2 = ws[O_A2+t]*ri;
    ca1[t] = a1; cb1[t] = ws[O_B1+t] - a1*mu;
    ca2[t] = a2; cb2[t] = ws[O_B2+t] - a2*mu;
  }
  if(t < 64){ bg1p[t] = (t < 50) ? bg1[t] : 0.f; bg2p[t] = (t < 50) ? bg2[t] : 0.f; }
  for(int i = t; i < 1600; i += 256){         // 50 cl rows x 32 float4 over c
    int cl = i >> 5, cq = i & 31;
    float4 w1 = *(const float4*)&wg1[cl*128 + cq*4];
    float4 w2 = *(const float4*)&wg2[cl*128 + cq*4];
    int c0 = cq*4;
    lW1[(c0+0)*56+cl] = w1.x; lW1[(c0+1)*56+cl] = w1.y; lW1[(c0+2)*56+cl] = w1.z; lW1[(c0+3)*56+cl] = w1.w;
    lW2[(c0+0)*56+cl] = w2.x; lW2[(c0+1)*56+cl] = w2.y; lW2[(c0+2)*56+cl] = w2.z; lW2[(c0+3)*56+cl] = w2.w;
  }
  for(int i = t; i < 768; i += 256){          // zero cl pads 50..55
    int cl = 50 + i/128, c = i%128;
    lW1[c*56+cl] = 0.f; lW2[c*56+cl] = 0.f;
  }
  // persistent UCX accumulators: thread (dg 0..32, cg 0..6), d=dg*4, c=cg*8
  int dg = t % 33, cg = t / 33;               // valid when t < 231
  float ua[4][8];
  #pragma unroll
  for(int r = 0; r < 4; r++)
    #pragma unroll
    for(int i = 0; i < 8; i++) ua[r][i] = 0.f;
  int ig = t >> 4, jg = t & 15;
  int clb = ig*4, j4 = jg*4;
  float e[4][4];

  for(int st = 0; st < 8; st++){
    int nb = ch*500 + st*64;
    int lim = (st == 7) ? 52 : 64;
    __syncthreads();
    // stage x tile: lxt[n][d] raw (+zeros pad), lrv1/lrv2 = relu(affine)
    for(int i = t; i < 2048; i += 256){
      int c = i >> 4, jj = (i & 15)*4;
      float4 xv = make_float4(0.f,0.f,0.f,0.f);
      if(jj < lim) xv = *(const float4*)&x[(size_t)(b*128 + c)*4000 + nb + jj];
      lxt[(jj+0)*132 + c] = xv.x; lxt[(jj+1)*132 + c] = xv.y;
      lxt[(jj+2)*132 + c] = xv.z; lxt[(jj+3)*132 + c] = xv.w;
      float a1 = ca1[c], b1v = cb1[c], a2 = ca2[c], b2v = cb2[c];
      float4 r1, r2;
      r1.x = fmaxf(a1*xv.x + b1v, 0.f); r1.y = fmaxf(a1*xv.y + b1v, 0.f);
      r1.z = fmaxf(a1*xv.z + b1v, 0.f); r1.w = fmaxf(a1*xv.w + b1v, 0.f);
      r2.x = fmaxf(a2*xv.x + b2v, 0.f); r2.y = fmaxf(a2*xv.y + b2v, 0.f);
      r2.z = fmaxf(a2*xv.z + b2v, 0.f); r2.w = fmaxf(a2*xv.w + b2v, 0.f);
      *(float4*)&lrv1[c*64 + jj] = r1;
      *(float4*)&lrv2[c*64 + jj] = r2;
    }
    if(t < 64){
      lxt[t*132 + 128] = (t < lim) ? 1.f : 0.f;   // ones-row -> Z
      lxt[t*132 + 129] = 0.f; lxt[t*132 + 130] = 0.f; lxt[t*132 + 131] = 0.f;
    }
    __syncthreads();
    // E1 GEMM: rows 56 (ig<14) x cols 64
    if(ig < 14){
      #pragma unroll
      for(int r = 0; r < 4; r++){ e[r][0]=0.f; e[r][1]=0.f; e[r][2]=0.f; e[r][3]=0.f; }
      #pragma unroll 4
      for(int c = 0; c < 128; c++){
        float4 w = *(const float4*)&lW1[c*56 + clb];
        float4 v = *(const float4*)&lrv1[c*64 + j4];
        e[0][0] += w.x*v.x; e[0][1] += w.x*v.y; e[0][2] += w.x*v.z; e[0][3] += w.x*v.w;
        e[1][0] += w.y*v.x; e[1][1] += w.y*v.y; e[1][2] += w.y*v.z; e[1][3] += w.y*v.w;
        e[2][0] += w.z*v.x; e[2][1] += w.z*v.y; e[2][2] += w.z*v.z; e[2][3] += w.z*v.w;
        e[3][0] += w.w*v.x; e[3][1] += w.w*v.y; e[3][2] += w.w*v.z; e[3][3] += w.w*v.w;
      }
    }
    __syncthreads();                 // E1 done reading lrv1 -> safe to overlay eU
    if(ig < 14){
      #pragma unroll
      for(int r = 0; r < 4; r++){
        float bias = bg1p[clb + r];
        float4 u;
        u.x = expf(e[r][0] + bias); u.y = expf(e[r][1] + bias);
        u.z = expf(e[r][2] + bias); u.w = expf(e[r][3] + bias);
        *(float4*)&lrv1[(clb + r)*64 + j4] = u;     // eU[cl][n]
      }
    }
    __syncthreads();
    // UCX accumulate: ua[d4..][c8..] += x[n][d] * eU[c][n]  (padded n: x==0)
    if(t < 231){
      int d4 = dg*4, cb8 = cg*8;
      #pragma unroll 2
      for(int n = 0; n < 64; n++){
        float4 xv = *(const float4*)&lxt[n*132 + d4];
        #pragma unroll
        for(int i = 0; i < 8; i++){
          float u = lrv1[(cb8 + i)*64 + n];
          ua[0][i] += xv.x*u; ua[1][i] += xv.y*u;
          ua[2][i] += xv.z*u; ua[3][i] += xv.w*u;
        }
      }
    }
    // E2 GEMM + global write
    if(ig < 14){
      #pragma unroll
      for(int r = 0; r < 4; r++){ e[r][0]=0.f; e[r][1]=0.f; e[r][2]=0.f; e[r][3]=0.f; }
      #pragma unroll 4
      for(int c = 0; c < 128; c++){
        float4 w = *(const float4*)&lW2[c*56 + clb];
        float4 v = *(const float4*)&lrv2[c*64 + j4];
        e[0][0] += w.x*v.x; e[0][1] += w.x*v.y; e[0][2] += w.x*v.z; e[0][3] += w.x*v.w;
        e[1][0] += w.y*v.x; e[1][1] += w.y*v.y; e[1][2] += w.y*v.z; e[1][3] += w.y*v.w;
        e[2][0] += w.z*v.x; e[2][1] += w.z*v.y; e[2][2] += w.z*v.z; e[2][3] += w.z*v.w;
        e[3][0] += w.w*v.x; e[3][1] += w.w*v.y; e[3][2] += w.w*v.z; e[3][3] += w.w*v.w;
      }
      if(j4 < lim){
        #pragma unroll
        for(int r = 0; r < 4; r++){
          int cl = clb + r;
          if(cl < 50){
            float bias = bg2p[cl];
            float4 o = make_float4(e[r][0]+bias, e[r][1]+bias, e[r][2]+bias, e[r][3]+bias);
            *(float4*)&ws[O_E2 + ((size_t)b*50 + cl)*4000 + nb + j4] = o;
          }
        }
      }
    }
  }
  // write partials [ch][b][132][56]
  if(t < 231){
    int d4 = dg*4, cb8 = cg*8;
    #pragma unroll
    for(int r = 0; r < 4; r++){
      size_t base = O_UCXP + ((size_t)(ch*64 + b)*132 + d4 + r)*56 + cb8;
      *(float4*)&ws[base]     = make_float4(ua[r][0], ua[r][1], ua[r][2], ua[r][3]);
      *(float4*)&ws[base + 4] = make_float4(ua[r][4], ua[r][5], ua[r][6], ua[r][7]);
    }
  }
}

// ---------------- K4: reduce partials, divide by Z -> cluster_x ----------------
__global__ __launch_bounds__(256) void k_cxred(float* __restrict__ ws){
  int b = blockIdx.x, t = threadIdx.x;
  __shared__ float zi[64];
  if(t < 50){
    float s = 0.f;
    for(int ch = 0; ch < 8; ch++)
      s += ws[O_UCXP + ((size_t)(ch*64 + b)*132 + 128)*56 + t];
    zi[t] = 1.f / s;
  }
  __syncthreads();
  for(int i = t; i < 6400; i += 256){
    int d = i / 50, c = i % 50;
    float s = 0.f;
    for(int ch = 0; ch < 8; ch++)
      s += ws[O_UCXP + ((size_t)(ch*64 + b)*132 + d)*56 + c];
    ws[O_CX + (size_t)b*6400 + d*50 + c] = s * zi[c];
  }
}

// ---------------- K5: qkv + qkv1 projections (512x128 @ 128x50 per b) ----------------
__global__ __launch_bounds__(256) void k_qkv(const float* __restrict__ qw,
                                             const float* __restrict__ qb,
                                             const float* __restrict__ q1w,
                                             const float* __restrict__ q1b,
                                             float* __restrict__ ws){
  int rt = blockIdx.x, b = blockIdx.y;        // 8 row-tiles of 64
  __shared__ float wl[64*130];                // [rl][k] pad 130
  __shared__ float cxl[128*52];               // [k][c]
  int t = threadIdx.x;
  for(int i = t; i < 2048; i += 256){
    int rl = i >> 5, kq = i & 31, row = rt*64 + rl;
    float4 w = (row < 128) ? *(const float4*)&qw[row*128 + kq*4]
                           : *(const float4*)&q1w[(row-128)*128 + kq*4];
    int k0 = kq*4;
    wl[rl*130 + k0+0] = w.x; wl[rl*130 + k0+1] = w.y;
    wl[rl*130 + k0+2] = w.z; wl[rl*130 + k0+3] = w.w;
  }
  for(int i = t; i < 6656; i += 256){
    int k = i / 52, c = i % 52;
    cxl[i] = (c < 50) ? ws[O_CX + (size_t)b*6400 + k*50 + c] : 0.f;
  }
  __syncthreads();
  int ig = t & 15, cg = t >> 4;               // rows ig*4, cols cg*4 (cg<13)
  float acc[4][4];
  #pragma unroll
  for(int r = 0; r < 4; r++){ acc[r][0]=0.f; acc[r][1]=0.f; acc[r][2]=0.f; acc[r][3]=0.f; }
  if(cg < 13){
    int rb = ig*4, cb = cg*4;
    #pragma unroll 4
    for(int k = 0; k < 128; k++){
      float4 cv = *(const float4*)&cxl[k*52 + cb];
      float w0 = wl[(rb+0)*130 + k], w1 = wl[(rb+1)*130 + k];
      float w2 = wl[(rb+2)*130 + k], w3 = wl[(rb+3)*130 + k];
      acc[0][0] += w0*cv.x; acc[0][1] += w0*cv.y; acc[0][2] += w0*cv.z; acc[0][3] += w0*cv.w;
      acc[1][0] += w1*cv.x; acc[1][1] += w1*cv.y; acc[1][2] += w1*cv.z; acc[1][3] += w1*cv.w;
      acc[2][0] += w2*cv.x; acc[2][1] += w2*cv.y; acc[2][2] += w2*cv.z; acc[2][3] += w2*cv.w;
      acc[3][0] += w3*cv.x; acc[3][1] += w3*cv.y; acc[3][2] += w3*cv.z; acc[3][3] += w3*cv.w;
    }
    #pragma unroll
    for(int r = 0; r < 4; r++){
      int row = rt*64 + ig*4 + r;
      size_t base; float bias;
      if(row < 128){
        int h = row >> 5;
        bias = qb[row];
        base = O_XT + (size_t)(b*4 + h)*1600 + (row & 31);
      }else{
        int r2 = row - 128, h = r2/96, j = r2%96, kind = j >> 5, dd = j & 31;
        bias = q1b[r2];
        base = (kind==0 ? O_QT : kind==1 ? O_KT : O_VT) + (size_t)(b*4 + h)*1600 + dd;
      }
      #pragma unroll
      for(int s = 0; s < 4; s++){
        int c = cg*4 + s;
        if(c < 50) ws[base + (size_t)c*32] = acc[r][s] + bias;
      }
    }
  }
}

// ---------------- K6: knn (top-9, jax tie order) + edge + conv1 ----------------
__global__ __launch_bounds__(256) void k_knn(const float* __restrict__ g1w,
                                             const float* __restrict__ g1bias,
                                             float* __restrict__ ws){
  int h = blockIdx.x, b = blockIdx.y;
  __shared__ float xtl[50][33];
  __shared__ float pdl[50][52];
  __shared__ float sql[50];
  __shared__ int   idxl[50][9];
  __shared__ float w1l[6144];                 // [(i*3+t)*32+o]
  int t = threadIdx.x;
  const float* xtg = ws + O_XT + (size_t)(b*4 + h)*1600;
  for(int i = t; i < 1600; i += 256) xtl[i >> 5][i & 31] = xtg[i];
  for(int i = t; i < 6144; i += 256){
    int o = i / 192, r = i % 192, ii = r / 3, tt = r % 3;
    w1l[(ii*3 + tt)*32 + o] = g1w[(size_t)h*6144 + i];
  }
  __syncthreads();
  if(t < 50){
    float s = 0.f;
    for(int d = 0; d < 32; d++){ float v = xtl[t][d]; s += v*v; }
    sql[t] = s;
  }
  __syncthreads();
  for(int i = t; i < 2500; i += 256){
    int n = i / 50, m = i % 50;
    float s = 0.f;
    for(int d = 0; d < 32; d++) s += xtl[n][d]*xtl[m][d];
    pdl[n][m] = 2.f*s - sql[n] - sql[m];
  }
  __syncthreads();
  if(t < 50){
    float pv = INFINITY; int pi = -1;
    for(int k = 0; k < 9; k++){
      float bv = -INFINITY; int bi = 1000;
      for(int m = 0; m < 50; m++){
        float v = pdl[t][m];
        bool elig = (v < pv) || (v == pv && m > pi);
        if(elig && (v > bv || (v == bv && m < bi))){ bv = v; bi = m; }
      }
      idxl[t][k] = bi; pv = bv; pi = bi;
    }
  }
  __syncthreads();
  if(t < 150){
    int n = t / 3, jw = t % 3;
    float acc[32];
    #pragma unroll
    for(int o = 0; o < 32; o++) acc[o] = 0.f;
    for(int t3 = 0; t3 < 3; t3++){
      int kx = idxl[n][jw*3 + t3];
      for(int ii = 0; ii < 32; ii++){
        float c0 = xtl[n][ii];
        float c1 = c0 - xtl[kx][ii];
        const float* wr0 = w1l + (ii*3 + t3)*32;
        const float* wr1 = w1l + ((ii+32)*3 + t3)*32;
        #pragma unroll
        for(int o = 0; o < 32; o++) acc[o] += c0*wr0[o] + c1*wr1[o];
      }
    }
    float* out = ws + O_H1 + ((size_t)(b*4 + h)*150 + n*3 + jw)*32;
    #pragma unroll
    for(int o = 0; o < 32; o++) out[o] = acc[o] + g1bias[h*32 + o];
  }
}

// ---------------- K7: BN1 stats ----------------
__global__ void k_bn1p(float* __restrict__ ws){
  int b = blockIdx.x, t = threadIdx.x;
  int p = t & 127, half = t >> 7;
  int h = p >> 5, o = p & 31;
  const float* src = ws + O_H1 + (size_t)b*19200;
  float s = 0.f, sq = 0.f;
  for(int nj = half*75; nj < half*75 + 75; nj++){
    float v = src[(h*150 + nj)*32 + o];
    s += v; sq += v*v;
  }
  __shared__ float ls[256], lq[256];
  ls[t] = s; lq[t] = sq; __syncthreads();
  if(t < 128){
    ws[O_P1 + b*256 + p]       = ls[t] + ls[t+128];
    ws[O_P1 + b*256 + 128 + p] = lq[t] + lq[t+128];
  }
}

__global__ void k_bn1f(const float* g, const float* be, float* __restrict__ ws){
  int t = threadIdx.x;
  if(t < 128){
    float s = 0.f, sq = 0.f;
    for(int b = 0; b < 64; b++){ s += ws[O_P1 + b*256 + t]; sq += ws[O_P1 + b*256 + 128 + t]; }
    float mean = s * (1.f/9600.f), var = sq * (1.f/9600.f) - mean*mean;
    float sc = g[t] * rsqrtf(var + 1e-5f);
    ws[O_BN1S+t] = sc; ws[O_BN1T+t] = be[t] - sc*mean;
  }
}

// ---------------- K8: BN1+relu then conv2 (1x3) + BN2 partials ----------------
__global__ __launch_bounds__(256) void k_conv2(const float* __restrict__ g2w,
                                               const float* __restrict__ g2bias,
                                               float* __restrict__ ws){
  int h = blockIdx.x, b = blockIdx.y;
  __shared__ float hl[150][33];
  __shared__ float w2l[3072];
  __shared__ float rs[8][32], rq[8][32];
  int t = threadIdx.x;
  const float* h1p = ws + O_H1 + (size_t)(b*4 + h)*4800;
  for(int i = t; i < 4800; i += 256){
    int nj = i >> 5, ii = i & 31;
    hl[nj][ii] = fmaxf(ws[O_BN1S + h*32 + ii]*h1p[i] + ws[O_BN1T + h*32 + ii], 0.f);
  }
  for(int i = t; i < 3072; i += 256){
    int o = i / 96, r = i % 96, ii = r / 3, tt = r % 3;
    w2l[(ii*3 + tt)*32 + o] = g2w[(size_t)h*3072 + i];
  }
  __syncthreads();
  int o = t & 31, ng = t >> 5;
  float bias = g2bias[h*32 + o];
  float s = 0.f, sq = 0.f;
  for(int n = ng; n < 50; n += 8){
    float acc = 0.f;
    for(int t3 = 0; t3 < 3; t3++){
      const float* hr = hl[n*3 + t3];
      #pragma unroll
      for(int ii = 0; ii < 32; ii++) acc += hr[ii] * w2l[(ii*3 + t3)*32 + o];
    }
    acc += bias;
    ws[O_H2 + ((size_t)(b*4 + h)*50 + n)*32 + o] = acc;
    s += acc; sq += acc*acc;
  }
  rs[ng][o] = s; rq[ng][o] = sq; __syncthreads();
  if(t < 32){
    float S = 0.f, Q = 0.f;
    for(int g2 = 0; g2 < 8; g2++){ S += rs[g2][t]; Q += rq[g2][t]; }
    ws[O_P2 + (b*4 + h)*64 + t]      = S;
    ws[O_P2 + (b*4 + h)*64 + 32 + t] = Q;
  }
}

__global__ void k_bn2f(const float* g, const float* be, float* __restrict__ ws){
  int t = threadIdx.x;
  if(t < 128){
    int h = t >> 5, o = t & 31;
    float s = 0.f, sq = 0.f;
    for(int b = 0; b < 64; b++){
      s  += ws[O_P2 + (size_t)(b*4 + h)*64 + o];
      sq += ws[O_P2 + (size_t)(b*4 + h)*64 + 32 + o];
    }
    float mean = s * (1.f/3200.f), var = sq * (1.f/3200.f) - mean*mean;
    float sc = g[t] * rsqrtf(var + 1e-5f);
    ws[O_BN2S+t] = sc; ws[O_BN2T+t] = be[t] - sc*mean;
  }
}

// ---------------- K9: tiny attention + assemble cat [b][256][50] ----------------
__global__ __launch_bounds__(256) void k_attn(float* __restrict__ ws){
  int h = blockIdx.x, b = blockIdx.y;
  __shared__ float qtl[50][33], ktl[50][33], vtl[50][33], al[50][52];
  int t = threadIdx.x;
  size_t base = (size_t)(b*4 + h)*1600;
  for(int i = t; i < 1600; i += 256){
    int n = i >> 5, d = i & 31;
    qtl[n][d] = ws[O_QT + base + i];
    ktl[n][d] = ws[O_KT + base + i];
    vtl[n][d] = ws[O_VT + base + i];
  }
  __syncthreads();
  for(int i = t; i < 2500; i += 256){
    int n = i / 50, m = i % 50;
    float s = 0.f;
    for(int d = 0; d < 32; d++) s += qtl[n][d]*ktl[m][d];
    al[n][m] = s * 0.17677669529663687f;
  }
  __syncthreads();
  if(t < 50){
    float m = -INFINITY;
    for(int j = 0; j < 50; j++) m = fmaxf(m, al[t][j]);
    float s = 0.f;
    for(int j = 0; j < 50; j++){ float e = expf(al[t][j] - m); al[t][j] = e; s += e; }
    float inv = 1.f/s;
    for(int j = 0; j < 50; j++) al[t][j] *= inv;
  }
  __syncthreads();
  for(int i = t; i < 1600; i += 256){
    int n = i >> 5, d = i & 31;
    float gacc = 0.f;
    for(int m = 0; m < 50; m++) gacc += al[n][m]*vtl[m][d];
    ws[O_CAT + ((size_t)b*256 + h*64 + 32 + d)*50 + n] = gacc;
    float l = fmaxf(ws[O_BN2S + h*32 + d]*ws[O_H2 + ((size_t)(b*4 + h)*50 + n)*32 + d] + ws[O_BN2T + h*32 + d], 0.f);
    ws[O_CAT + ((size_t)b*256 + h*64 + d)*50 + n] = l;
  }
}

// ---------------- K10: pres2[b][c][o] = (M @ cat)[o][c] + vproj[o] ----------------
__global__ __launch_bounds__(256) void k_res(float* __restrict__ ws){
  int b = blockIdx.x;
  __shared__ float mtl[64*132];    // [k][o] pad 132
  __shared__ float catl[64*52];    // [k][c]
  __shared__ float vp[128];
  int t = threadIdx.x;
  if(t < 128) vp[t] = ws[O_VPROJ + t];
  int og = t >> 4, cg = t & 15;    // ob = og*8 (128 o), cb = cg*4 (cg<13)
  int ob = og*8, cb = cg*4;
  float acc[8][4];
  #pragma unroll
  for(int r = 0; r < 8; r++){ acc[r][0]=0.f; acc[r][1]=0.f; acc[r][2]=0.f; acc[r][3]=0.f; }
  for(int kc = 0; kc < 4; kc++){
    int k0 = kc*64;
    __syncthreads();
    for(int i = t; i < 2048; i += 256){
      int k = i >> 5, oq = i & 31;
      float4 m = *(const float4*)&ws[O_MT + (size_t)(k0 + k)*128 + oq*4];
      *(float4*)&mtl[k*132 + oq*4] = m;
    }
    for(int i = t; i < 3328; i += 256){
      int k = i / 52, c = i % 52;
      catl[i] = (c < 50) ? ws[O_CAT + (size_t)b*12800 + (k0 + k)*50 + c] : 0.f;
    }
    __syncthreads();
    if(cg < 13){
      #pragma unroll 2
      for(int k = 0; k < 64; k++){
        float4 m0 = *(const float4*)&mtl[k*132 + ob];
        float4 m1 = *(const float4*)&mtl[k*132 + ob + 4];
        float4 cv = *(const float4*)&catl[k*52 + cb];
        acc[0][0] += m0.x*cv.x; acc[0][1] += m0.x*cv.y; acc[0][2] += m0.x*cv.z; acc[0][3] += m0.x*cv.w;
        acc[1][0] += m0.y*cv.x; acc[1][1] += m0.y*cv.y; acc[1][2] += m0.y*cv.z; acc[1][3] += m0.y*cv.w;
        acc[2][0] += m0.z*cv.x; acc[2][1] += m0.z*cv.y; acc[2][2] += m0.z*cv.z; acc[2][3] += m0.z*cv.w;
        acc[3][0] += m0.w*cv.x; acc[3][1] += m0.w*cv.y; acc[3][2] += m0.w*cv.z; acc[3][3] += m0.w*cv.w;
        acc[4][0] += m1.x*cv.x; acc[4][1] += m1.x*cv.y; acc[4][2] += m1.x*cv.z; acc[4][3] += m1.x*cv.w;
        acc[5][0] += m1.y*cv.x; acc[5][1] += m1.y*cv.y; acc[5][2] += m1.y*cv.z; acc[5][3] += m1.y*cv.w;
        acc[6][0] += m1.z*cv.x; acc[6][1] += m1.z*cv.y; acc[6][2] += m1.z*cv.z; acc[6][3] += m1.z*cv.w;
        acc[7][0] += m1.w*cv.x; acc[7][1] += m1.w*cv.y; acc[7][2] += m1.w*cv.z; acc[7][3] += m1.w*cv.w;
      }
    }
  }
  if(cg < 13){
    #pragma unroll
    for(int s = 0; s < 4; s++){
      int c = cb + s;
      if(c < 50){
        float4 o0 = make_float4(acc[0][s]+vp[ob+0], acc[1][s]+vp[ob+1], acc[2][s]+vp[ob+2], acc[3][s]+vp[ob+3]);
        float4 o1 = make_float4(acc[4][s]+vp[ob+4], acc[5][s]+vp[ob+5], acc[6][s]+vp[ob+6], acc[7][s]+vp[ob+7]);
        *(float4*)&ws[O_PRES2 + (size_t)b*6400 + c*128 + ob]     = o0;
        *(float4*)&ws[O_PRES2 + (size_t)b*6400 + c*128 + ob + 4] = o1;
      }
    }
  }
}

// ---------------- K11: out = pres2 @ softmax_cl(embed2) + proj_b ----------------
__global__ __launch_bounds__(256) void k_out(const float* __restrict__ projb,
                                             float* __restrict__ ws,
                                             float* __restrict__ out){
  int nt = blockIdx.x, b = blockIdx.y;
  int n0 = nt*64;
  __shared__ float sl[50*64];      // [c][j]
  __shared__ float p2l[50*132];    // [c][o] pad 132
  __shared__ float pb[128];
  int t = threadIdx.x;
  for(int i = t; i < 3200; i += 256){
    int c = i >> 6, j = i & 63, n = n0 + j;
    sl[i] = (n < 4000) ? ws[O_E2 + ((size_t)b*50 + c)*4000 + n] : 0.f;
  }
  for(int i = t; i < 6400; i += 256){
    int c = i >> 7, o = i & 127;
    p2l[c*132 + o] = ws[O_PRES2 + (size_t)b*6400 + c*128 + o];
  }
  if(t < 128) pb[t] = projb[t];
  __syncthreads();
  if(t < 64){
    int j = t;
    float m = -INFINITY;
    for(int c = 0; c < 50; c++) m = fmaxf(m, sl[c*64 + j]);
    float s = 0.f;
    for(int c = 0; c < 50; c++){ float e = expf(sl[c*64 + j] - m); sl[c*64 + j] = e; s += e; }
    float inv = 1.f/s;
    for(int c = 0; c < 50; c++) sl[c*64 + j] *= inv;
  }
  __syncthreads();
  int og = t >> 4, jg = t & 15;
  int ob = og*8, j4 = jg*4;
  float acc[8][4];
  #pragma unroll
  for(int r = 0; r < 8; r++){ acc[r][0]=0.f; acc[r][1]=0.f; acc[r][2]=0.f; acc[r][3]=0.f; }
  #pragma unroll 2
  for(int c = 0; c < 50; c++){
    float4 sv = *(const float4*)&sl[c*64 + j4];
    float4 p0 = *(const float4*)&p2l[c*132 + ob];
    float4 p1 = *(const float4*)&p2l[c*132 + ob + 4];
    acc[0][0] += p0.x*sv.x; acc[0][1] += p0.x*sv.y; acc[0][2] += p0.x*sv.z; acc[0][3] += p0.x*sv.w;
    acc[1][0] += p0.y*sv.x; acc[1][1] += p0.y*sv.y; acc[1][2] += p0.y*sv.z; acc[1][3] += p0.y*sv.w;
    acc[2][0] += p0.z*sv.x; acc[2][1] += p0.z*sv.y; acc[2][2] += p0.z*sv.z; acc[2][3] += p0.z*sv.w;
    acc[3][0] += p0.w*sv.x; acc[3][1] += p0.w*sv.y; acc[3][2] += p0.w*sv.z; acc[3][3] += p0.w*sv.w;
    acc[4][0] += p1.x*sv.x; acc[4][1] += p1.x*sv.y; acc[4][2] += p1.x*sv.z; acc[4][3] += p1.x*sv.w;
    acc[5][0] += p1.y*sv.x; acc[5][1] += p1.y*sv.y; acc[5][2] += p1.y*sv.z; acc[5][3] += p1.y*sv.w;
    acc[6][0] += p1.z*sv.x; acc[6][1] += p1.z*sv.y; acc[6][2] += p1.z*sv.z; acc[6][3] += p1.z*sv.w;
    acc[7][0] += p1.w*sv.x; acc[7][1] += p1.w*sv.y; acc[7][2] += p1.w*sv.z; acc[7][3] += p1.w*sv.w;
  }
  int n = n0 + j4;
  if(n < 4000){
    #pragma unroll
    for(int r = 0; r < 8; r++){
      float bv = pb[ob + r];
      float4 o = make_float4(acc[r][0]+bv, acc[r][1]+bv, acc[r][2]+bv, acc[r][3]+bv);
      *(float4*)&out[(size_t)(b*128 + ob + r)*4000 + n] = o;
    }
  }
}

extern "C" void kernel_launch(void* const* d_in, const int* in_sizes, int n_in,
                              void* d_out, int out_size, void* d_ws, size_t ws_size,
                              hipStream_t stream){
  (void)in_sizes; (void)n_in; (void)out_size; (void)ws_size;
  const float* x      = (const float*)d_in[0];
  const float* wg1    = (const float*)d_in[1];
  const float* bg1    = (const float*)d_in[2];
  const float* g1g    = (const float*)d_in[3];
  const float* g1b    = (const float*)d_in[4];
  const float* wg2    = (const float*)d_in[5];
  const float* bg2    = (const float*)d_in[6];
  const float* g2g    = (const float*)d_in[7];
  const float* g2b    = (const float*)d_in[8];
  const float* qkvw   = (const float*)d_in[9];
  const float* qkvb   = (const float*)d_in[10];
  const float* qkv1w  = (const float*)d_in[11];
  const float* qkv1b  = (const float*)d_in[12];
  const float* gc1w   = (const float*)d_in[13];
  const float* gc1bias= (const float*)d_in[14];
  const float* gc1g   = (const float*)d_in[15];
  const float* gc1be  = (const float*)d_in[16];
  const float* gc2w   = (const float*)d_in[17];
  const float* gc2bias= (const float*)d_in[18];
  const float* gc2g   = (const float*)d_in[19];
  const float* gc2be  = (const float*)d_in[20];
  const float* presw  = (const float*)d_in[21];
  const float* presb  = (const float*)d_in[22];
  const float* projw  = (const float*)d_in[23];
  const float* projb  = (const float*)d_in[24];
  float* ws = (float*)d_ws;
  float* out = (float*)d_out;

  k_rowstats<<<8192, 256, 0, stream>>>(x, ws);
  k_prep<<<1, 256, 0, stream>>>(g1g, g1b, g2g, g2b, presb, projw, ws);
  k_mprep<<<128, 256, 0, stream>>>(presw, ws);
  k_fused<<<dim3(8, 64), 256, 0, stream>>>(x, wg1, bg1, wg2, bg2, ws);
  k_cxred<<<64, 256, 0, stream>>>(ws);
  k_qkv<<<dim3(8, 64), 256, 0, stream>>>(qkvw, qkvb, qkv1w, qkv1b, ws);
  k_knn<<<dim3(4, 64), 256, 0, stream>>>(gc1w, gc1bias, ws);
  k_bn1p<<<64, 256, 0, stream>>>(ws);
  k_bn1f<<<1, 128, 0, stream>>>(gc1g, gc1be, ws);
  k_conv2<<<dim3(4, 64), 256, 0, stream>>>(gc2w, gc2bias, ws);
  k_bn2f<<<1, 128, 0, stream>>>(gc2g, gc2be, ws);
  k_attn<<<dim3(4, 64), 256, 0, stream>>>(ws);
  k_res<<<64, 256, 0, stream>>>(ws);
  k_out<<<dim3(63, 64), 256, 0, stream>>>(projb, ws, out);
}